// Round 1
// baseline (506.860 us; speedup 1.0000x reference)
//
#include <hip/hip_runtime.h>
#include <math.h>

#define Bb 2
#define Ll 2048
#define Dm 1024
#define Ns 16
#define Rr 64
#define Ee 96          // DT_RANK + 2*D_STATE
#define CH 32          // chunks
#define CL 64          // chunk length = Ll / CH

// ---------------- Kernel A: xp[bl][e] = sum_d x[bl][d] * xw[e][d] ----------------
__global__ void k_xproj(const float* __restrict__ x, const float* __restrict__ xw,
                        float* __restrict__ xp) {
    int gid = blockIdx.x * blockDim.x + threadIdx.x;           // Bb*Ll*Ee = 393216
    int e  = gid % Ee;
    int bl = gid / Ee;
    const float4* xr = (const float4*)(x  + (size_t)bl * Dm);
    const float4* wr = (const float4*)(xw + (size_t)e  * Dm);
    float acc = 0.f;
#pragma unroll 4
    for (int k = 0; k < Dm / 4; ++k) {
        float4 a = xr[k], b = wr[k];
        acc += a.x * b.x + a.y * b.y + a.z * b.z + a.w * b.w;
    }
    xp[gid] = acc;
}

// ------------- Kernel B: delta[bl][d] = softplus(dot(xp[bl][:64], dtw[d]) + dtb[d]) -------------
__global__ void k_delta(const float* __restrict__ xp, const float* __restrict__ dtw,
                        const float* __restrict__ dtb, float* __restrict__ delta) {
    int gid = blockIdx.x * blockDim.x + threadIdx.x;           // Bb*Ll*Dm = 4194304
    int d  = gid & (Dm - 1);
    int bl = gid >> 10;
    const float4* xr = (const float4*)(xp  + (size_t)bl * Ee); // first 64 floats = d_rank
    const float4* wr = (const float4*)(dtw + (size_t)d  * Rr);
    float acc = dtb[d];
#pragma unroll
    for (int k = 0; k < Rr / 4; ++k) {
        float4 a = xr[k], b = wr[k];
        acc += a.x * b.x + a.y * b.y + a.z * b.z + a.w * b.w;
    }
    // numerically-stable softplus: max(z,0) + log1p(exp(-|z|))
    float sp = fmaxf(acc, 0.f) + log1pf(__expf(-fabsf(acc)));
    delta[gid] = sp;
}

// ------------- Kernel C1: per-chunk local scan (h0 = 0) -> E (end state), S (sum delta) -------------
__global__ void k_scan_part(const float* __restrict__ delta, const float* __restrict__ x,
                            const float* __restrict__ xp, const float* __restrict__ A_log,
                            float* __restrict__ Ec, float* __restrict__ Sc) {
    int bx    = blockIdx.x;            // 256 blocks: b*128 + chunk*4 + dblk
    int dblk  = bx & 3;
    int chunk = (bx >> 2) & (CH - 1);
    int b     = bx >> 7;
    int d     = dblk * 256 + threadIdx.x;

    float a[Ns], h[Ns];
#pragma unroll
    for (int n = 0; n < Ns; ++n) {
        a[n] = -__expf(A_log[d * Ns + n]);
        h[n] = 0.f;
    }
    float sum_delta = 0.f;
    int t0 = chunk * CL;
    for (int i = 0; i < CL; ++i) {
        size_t bl = (size_t)b * Ll + (t0 + i);
        float dl = delta[bl * Dm + d];
        float xv = x[bl * Dm + d];
        float dx = dl * xv;
        sum_delta += dl;
        const float4* Bp = (const float4*)(xp + bl * Ee + Rr);
        float4 Bq[4] = {Bp[0], Bp[1], Bp[2], Bp[3]};
        const float* Bv = (const float*)Bq;
#pragma unroll
        for (int n = 0; n < Ns; ++n) {
            float dA = __expf(dl * a[n]);
            h[n] = dA * h[n] + dx * Bv[n];
        }
    }
    size_t base = ((size_t)b * CH + chunk) * Dm + d;
    float4* Ep = (float4*)(Ec + base * Ns);
    Ep[0] = make_float4(h[0],  h[1],  h[2],  h[3]);
    Ep[1] = make_float4(h[4],  h[5],  h[6],  h[7]);
    Ep[2] = make_float4(h[8],  h[9],  h[10], h[11]);
    Ep[3] = make_float4(h[12], h[13], h[14], h[15]);
    Sc[base] = sum_delta;
}

// ------------- Kernel C2: sequential combine over chunks -> Hin (state entering each chunk) -------------
__global__ void k_combine(const float* __restrict__ Ec, const float* __restrict__ Sc,
                          const float* __restrict__ A_log, float* __restrict__ Hin) {
    int gid = blockIdx.x * blockDim.x + threadIdx.x;  // Bb*Dm*Ns = 32768
    int n = gid & (Ns - 1);
    int d = (gid >> 4) & (Dm - 1);
    int b = gid >> 14;
    float a = -__expf(A_log[d * Ns + n]);
    float h = 0.f;
    for (int c = 0; c < CH; ++c) {
        size_t base = ((size_t)b * CH + c) * Dm + d;
        Hin[base * Ns + n] = h;
        float P = __expf(a * Sc[base]);          // == prod_t exp(delta_t * a)
        h = P * h + Ec[base * Ns + n];
    }
}

// ------------- Kernel C3: full local scan from true h_in, emit y -------------
__global__ void k_scan_full(const float* __restrict__ delta, const float* __restrict__ x,
                            const float* __restrict__ xp, const float* __restrict__ A_log,
                            const float* __restrict__ Dp, const float* __restrict__ Hin,
                            float* __restrict__ out) {
    int bx    = blockIdx.x;
    int dblk  = bx & 3;
    int chunk = (bx >> 2) & (CH - 1);
    int b     = bx >> 7;
    int d     = dblk * 256 + threadIdx.x;

    float a[Ns], h[Ns];
#pragma unroll
    for (int n = 0; n < Ns; ++n)
        a[n] = -__expf(A_log[d * Ns + n]);

    size_t base = ((size_t)b * CH + chunk) * Dm + d;
    const float4* Hp = (const float4*)(Hin + base * Ns);
    {
        float4 h0 = Hp[0], h1 = Hp[1], h2 = Hp[2], h3 = Hp[3];
        h[0]=h0.x; h[1]=h0.y; h[2]=h0.z; h[3]=h0.w;
        h[4]=h1.x; h[5]=h1.y; h[6]=h1.z; h[7]=h1.w;
        h[8]=h2.x; h[9]=h2.y; h[10]=h2.z; h[11]=h2.w;
        h[12]=h3.x; h[13]=h3.y; h[14]=h3.z; h[15]=h3.w;
    }
    float Dval = Dp[d];
    int t0 = chunk * CL;
    for (int i = 0; i < CL; ++i) {
        size_t bl = (size_t)b * Ll + (t0 + i);
        float dl = delta[bl * Dm + d];
        float xv = x[bl * Dm + d];
        float dx = dl * xv;
        const float4* Bp = (const float4*)(xp + bl * Ee + Rr);
        float4 Bq[4] = {Bp[0], Bp[1], Bp[2], Bp[3]};
        const float* Bv = (const float*)Bq;
        const float4* Cp = (const float4*)(xp + bl * Ee + Rr + Ns);
        float4 Cq[4] = {Cp[0], Cp[1], Cp[2], Cp[3]};
        const float* Cv = (const float*)Cq;
        float y = 0.f;
#pragma unroll
        for (int n = 0; n < Ns; ++n) {
            float dA = __expf(dl * a[n]);
            h[n] = dA * h[n] + dx * Bv[n];
            y += h[n] * Cv[n];
        }
        out[bl * Dm + d] = y + xv * Dval;
    }
}

extern "C" void kernel_launch(void* const* d_in, const int* in_sizes, int n_in,
                              void* d_out, int out_size, void* d_ws, size_t ws_size,
                              hipStream_t stream) {
    const float* x     = (const float*)d_in[0];
    const float* A_log = (const float*)d_in[1];
    const float* Dp    = (const float*)d_in[2];
    const float* xw    = (const float*)d_in[3];
    const float* dtw   = (const float*)d_in[4];
    const float* dtb   = (const float*)d_in[5];
    float* out = (float*)d_out;
    float* ws  = (float*)d_ws;

    float* xp    = ws;                         // 4096*96      = 393216
    float* delta = xp + 393216;                // 4096*1024    = 4194304
    float* Ec    = delta + 4194304;            // 2*32*1024*16 = 1048576
    float* Sc    = Ec + 1048576;               // 2*32*1024    = 65536
    float* Hin   = Sc + 65536;                 // 2*32*1024*16 = 1048576
    // total: 6750208 floats = 27.0 MB of d_ws

    k_xproj    <<<dim3((Bb*Ll*Ee)/256), dim3(256), 0, stream>>>(x, xw, xp);
    k_delta    <<<dim3((Bb*Ll*Dm)/256), dim3(256), 0, stream>>>(xp, dtw, dtb, delta);
    k_scan_part<<<dim3(Bb*CH*(Dm/256)), dim3(256), 0, stream>>>(delta, x, xp, A_log, Ec, Sc);
    k_combine  <<<dim3((Bb*Dm*Ns)/256), dim3(256), 0, stream>>>(Ec, Sc, A_log, Hin);
    k_scan_full<<<dim3(Bb*CH*(Dm/256)), dim3(256), 0, stream>>>(delta, x, xp, A_log, Dp, Hin, out);
}

// Round 2
// 173.415 us; speedup vs baseline: 2.9228x; 2.9228x over previous
//
#include <hip/hip_runtime.h>
#include <math.h>

#define Bb 2
#define Ll 2048
#define Dm 1024
#define Ns 16
#define Rr 64
#define Ee 96          // DT_RANK + 2*D_STATE
#define CH 64          // chunks
#define CL 32          // chunk length = Ll / CH
#define XPS 8          // K-splits for xproj GEMM
#define BLK (Bb*Ll)    // 4096 rows

// ================= Kernel A: tiled GEMM  xp_part[ks][bl][e] = sum_{k in slice} x[bl][k]*xw[e][k] =================
// BM=128, BN=96 (full), K-slice=128 (2 chunks of 64). grid = 32 mtiles * 8 ks = 256 blocks.
__global__ void k_xproj(const float* __restrict__ x, const float* __restrict__ xw,
                        float* __restrict__ xp_part) {
    __shared__ float xs[128][65];
    __shared__ float wsh[96][65];
    int bx = blockIdx.x;
    int ks = bx & 7;
    int mt = bx >> 3;
    int i0 = mt * 128;
    int tid = threadIdx.x;
    int tx = tid & 15, ty = tid >> 4;     // 16x16 threads; tile 8(i) x 6(j) each

    float acc[8][6];
#pragma unroll
    for (int ii = 0; ii < 8; ++ii)
#pragma unroll
        for (int jj = 0; jj < 6; ++jj) acc[ii][jj] = 0.f;

    for (int kc = 0; kc < 2; ++kc) {
        int k0 = ks * 128 + kc * 64;
        // stage x tile: 128 rows x 64 k
        for (int t = tid; t < 2048; t += 256) {
            int r = t >> 4, cv = t & 15;
            float4 v = *(const float4*)(x + (size_t)(i0 + r) * Dm + k0 + cv * 4);
            xs[r][cv*4+0] = v.x; xs[r][cv*4+1] = v.y; xs[r][cv*4+2] = v.z; xs[r][cv*4+3] = v.w;
        }
        // stage w tile: 96 rows x 64 k
        for (int t = tid; t < 1536; t += 256) {
            int r = t >> 4, cv = t & 15;
            float4 v = *(const float4*)(xw + (size_t)r * Dm + k0 + cv * 4);
            wsh[r][cv*4+0] = v.x; wsh[r][cv*4+1] = v.y; wsh[r][cv*4+2] = v.z; wsh[r][cv*4+3] = v.w;
        }
        __syncthreads();
#pragma unroll 4
        for (int k = 0; k < 64; ++k) {
            float xv[8], wv[6];
#pragma unroll
            for (int ii = 0; ii < 8; ++ii) xv[ii] = xs[ty*8+ii][k];
#pragma unroll
            for (int jj = 0; jj < 6; ++jj) wv[jj] = wsh[tx*6+jj][k];
#pragma unroll
            for (int ii = 0; ii < 8; ++ii)
#pragma unroll
                for (int jj = 0; jj < 6; ++jj)
                    acc[ii][jj] = fmaf(xv[ii], wv[jj], acc[ii][jj]);
        }
        __syncthreads();
    }
#pragma unroll
    for (int ii = 0; ii < 8; ++ii)
#pragma unroll
        for (int jj = 0; jj < 6; ++jj)
            xp_part[((size_t)ks * BLK + (i0 + ty*8 + ii)) * Ee + tx*6 + jj] = acc[ii][jj];
}

// ================= Kernel A2: reduce K-splits =================
__global__ void k_xreduce(const float* __restrict__ xp_part, float* __restrict__ xp) {
    int gid = blockIdx.x * 256 + threadIdx.x;  // BLK*Ee = 393216
    float s = 0.f;
#pragma unroll
    for (int i = 0; i < XPS; ++i) s += xp_part[(size_t)i * (BLK*Ee) + gid];
    xp[gid] = s;
}

// ================= Kernel B: tiled GEMM + softplus  delta[bl][d] =================
// M=4096, N=1024, K=64. BM=64, BN=128. grid = 64 mtiles * 8 ntiles = 512 blocks.
__global__ void k_delta(const float* __restrict__ xp, const float* __restrict__ dtw,
                        const float* __restrict__ dtb, float* __restrict__ delta) {
    __shared__ float xs[64][65];
    __shared__ float wsh[128][65];
    int bx = blockIdx.x;
    int nt = bx & 7;
    int mt = bx >> 3;
    int i0 = mt * 64, j0 = nt * 128;
    int tid = threadIdx.x, tx = tid & 15, ty = tid >> 4;  // tile 4(i) x (4+4)(j)

    // stage xp tile: 64 rows x 64 k (first 64 of 96 cols)
    for (int t = tid; t < 1024; t += 256) {
        int r = t >> 4, cv = t & 15;
        float4 v = *(const float4*)(xp + (size_t)(i0 + r) * Ee + cv * 4);
        xs[r][cv*4+0] = v.x; xs[r][cv*4+1] = v.y; xs[r][cv*4+2] = v.z; xs[r][cv*4+3] = v.w;
    }
    // stage dtw tile: 128 rows(d) x 64 k
    for (int t = tid; t < 2048; t += 256) {
        int r = t >> 4, cv = t & 15;
        float4 v = *(const float4*)(dtw + (size_t)(j0 + r) * Rr + cv * 4);
        wsh[r][cv*4+0] = v.x; wsh[r][cv*4+1] = v.y; wsh[r][cv*4+2] = v.z; wsh[r][cv*4+3] = v.w;
    }
    __syncthreads();

    float acc[4][8];
#pragma unroll
    for (int ii = 0; ii < 4; ++ii)
#pragma unroll
        for (int jj = 0; jj < 8; ++jj) acc[ii][jj] = 0.f;

#pragma unroll 4
    for (int k = 0; k < 64; ++k) {
        float xv[4], wv[8];
#pragma unroll
        for (int ii = 0; ii < 4; ++ii) xv[ii] = xs[ty*4+ii][k];
#pragma unroll
        for (int g = 0; g < 2; ++g)
#pragma unroll
            for (int jj = 0; jj < 4; ++jj) wv[g*4+jj] = wsh[g*64 + tx*4 + jj][k];
#pragma unroll
        for (int ii = 0; ii < 4; ++ii)
#pragma unroll
            for (int jj = 0; jj < 8; ++jj)
                acc[ii][jj] = fmaf(xv[ii], wv[jj], acc[ii][jj]);
    }

#pragma unroll
    for (int g = 0; g < 2; ++g) {
        int d0 = j0 + g*64 + tx*4;
        float4 bias = *(const float4*)(dtb + d0);
#pragma unroll
        for (int ii = 0; ii < 4; ++ii) {
            int bl = i0 + ty*4 + ii;
            float z0 = acc[ii][g*4+0] + bias.x;
            float z1 = acc[ii][g*4+1] + bias.y;
            float z2 = acc[ii][g*4+2] + bias.z;
            float z3 = acc[ii][g*4+3] + bias.w;
            float4 o;
            o.x = fmaxf(z0, 0.f) + log1pf(__expf(-fabsf(z0)));
            o.y = fmaxf(z1, 0.f) + log1pf(__expf(-fabsf(z1)));
            o.z = fmaxf(z2, 0.f) + log1pf(__expf(-fabsf(z2)));
            o.w = fmaxf(z3, 0.f) + log1pf(__expf(-fabsf(z3)));
            *(float4*)(delta + (size_t)bl * Dm + d0) = o;
        }
    }
}

// ================= Kernel C1: per-chunk local scan (h0=0) -> Ec, Sc =================
__global__ void k_scan_part(const float* __restrict__ delta, const float* __restrict__ x,
                            const float* __restrict__ xp, const float* __restrict__ A_log,
                            float* __restrict__ Ec, float* __restrict__ Sc) {
    int bx    = blockIdx.x;            // b*256 + chunk*4 + dblk ; grid = 512
    int dblk  = bx & 3;
    int chunk = (bx >> 2) & (CH - 1);
    int b     = bx >> 8;
    int d     = dblk * 256 + threadIdx.x;

    float a[Ns], h[Ns];
#pragma unroll
    for (int n = 0; n < Ns; ++n) {
        a[n] = -__expf(A_log[d * Ns + n]);
        h[n] = 0.f;
    }
    float sum_delta = 0.f;
    int t0 = chunk * CL;
    for (int i = 0; i < CL; ++i) {
        size_t bl = (size_t)b * Ll + (t0 + i);
        float dl = delta[bl * Dm + d];
        float xv = x[bl * Dm + d];
        float dx = dl * xv;
        sum_delta += dl;
        const float4* Bp = (const float4*)(xp + bl * Ee + Rr);
        float4 Bq[4] = {Bp[0], Bp[1], Bp[2], Bp[3]};
        const float* Bv = (const float*)Bq;
#pragma unroll
        for (int n = 0; n < Ns; ++n) {
            float dA = __expf(dl * a[n]);
            h[n] = dA * h[n] + dx * Bv[n];
        }
    }
    size_t base = ((size_t)b * CH + chunk) * Dm + d;
    float4* Ep = (float4*)(Ec + base * Ns);
    Ep[0] = make_float4(h[0],  h[1],  h[2],  h[3]);
    Ep[1] = make_float4(h[4],  h[5],  h[6],  h[7]);
    Ep[2] = make_float4(h[8],  h[9],  h[10], h[11]);
    Ep[3] = make_float4(h[12], h[13], h[14], h[15]);
    Sc[base] = sum_delta;
}

// ================= Kernel C2: sequential combine over chunks -> Hin =================
__global__ void k_combine(const float* __restrict__ Ec, const float* __restrict__ Sc,
                          const float* __restrict__ A_log, float* __restrict__ Hin) {
    int gid = blockIdx.x * blockDim.x + threadIdx.x;  // Bb*Dm*Ns = 32768
    int n = gid & (Ns - 1);
    int d = (gid >> 4) & (Dm - 1);
    int b = gid >> 14;
    float a = -__expf(A_log[d * Ns + n]);
    float h = 0.f;
    for (int c = 0; c < CH; ++c) {
        size_t base = ((size_t)b * CH + c) * Dm + d;
        Hin[base * Ns + n] = h;
        float P = __expf(a * Sc[base]);
        h = P * h + Ec[base * Ns + n];
    }
}

// ================= Kernel C3: full scan from true h_in, emit y =================
__global__ void k_scan_full(const float* __restrict__ delta, const float* __restrict__ x,
                            const float* __restrict__ xp, const float* __restrict__ A_log,
                            const float* __restrict__ Dp, const float* __restrict__ Hin,
                            float* __restrict__ out) {
    int bx    = blockIdx.x;
    int dblk  = bx & 3;
    int chunk = (bx >> 2) & (CH - 1);
    int b     = bx >> 8;
    int d     = dblk * 256 + threadIdx.x;

    float a[Ns], h[Ns];
#pragma unroll
    for (int n = 0; n < Ns; ++n)
        a[n] = -__expf(A_log[d * Ns + n]);

    size_t base = ((size_t)b * CH + chunk) * Dm + d;
    const float4* Hp = (const float4*)(Hin + base * Ns);
    {
        float4 h0 = Hp[0], h1 = Hp[1], h2 = Hp[2], h3 = Hp[3];
        h[0]=h0.x; h[1]=h0.y; h[2]=h0.z; h[3]=h0.w;
        h[4]=h1.x; h[5]=h1.y; h[6]=h1.z; h[7]=h1.w;
        h[8]=h2.x; h[9]=h2.y; h[10]=h2.z; h[11]=h2.w;
        h[12]=h3.x; h[13]=h3.y; h[14]=h3.z; h[15]=h3.w;
    }
    float Dval = Dp[d];
    int t0 = chunk * CL;
    for (int i = 0; i < CL; ++i) {
        size_t bl = (size_t)b * Ll + (t0 + i);
        float dl = delta[bl * Dm + d];
        float xv = x[bl * Dm + d];
        float dx = dl * xv;
        const float4* Bp = (const float4*)(xp + bl * Ee + Rr);
        float4 Bq[4] = {Bp[0], Bp[1], Bp[2], Bp[3]};
        const float* Bv = (const float*)Bq;
        const float4* Cp = (const float4*)(xp + bl * Ee + Rr + Ns);
        float4 Cq[4] = {Cp[0], Cp[1], Cp[2], Cp[3]};
        const float* Cv = (const float*)Cq;
        float y = 0.f;
#pragma unroll
        for (int n = 0; n < Ns; ++n) {
            float dA = __expf(dl * a[n]);
            h[n] = dA * h[n] + dx * Bv[n];
            y += h[n] * Cv[n];
        }
        out[bl * Dm + d] = y + xv * Dval;
    }
}

extern "C" void kernel_launch(void* const* d_in, const int* in_sizes, int n_in,
                              void* d_out, int out_size, void* d_ws, size_t ws_size,
                              hipStream_t stream) {
    const float* x     = (const float*)d_in[0];
    const float* A_log = (const float*)d_in[1];
    const float* Dp    = (const float*)d_in[2];
    const float* xw    = (const float*)d_in[3];
    const float* dtw   = (const float*)d_in[4];
    const float* dtb   = (const float*)d_in[5];
    float* out = (float*)d_out;
    float* ws  = (float*)d_ws;

    // layout (floats):
    //   xp    : 393216
    //   delta : 4194304
    //   S3    : shared region, 4325376 floats
    //     phase 1: xp_part (8 * 393216 = 3145728)  [dead after k_xreduce]
    //     phase 2: Ec (2097152) | Sc (131072) | Hin (2097152)
    float* xp      = ws;
    float* delta   = xp + 393216;
    float* S3      = delta + 4194304;
    float* xp_part = S3;
    float* Ec      = S3;
    float* Sc      = Ec + 2097152;
    float* Hin     = Sc + 131072;
    // total 8,912,896 floats = 35.7 MB

    k_xproj    <<<dim3(256),  dim3(256), 0, stream>>>(x, xw, xp_part);
    k_xreduce  <<<dim3(1536), dim3(256), 0, stream>>>(xp_part, xp);
    k_delta    <<<dim3(512),  dim3(256), 0, stream>>>(xp, dtw, dtb, delta);
    k_scan_part<<<dim3(512),  dim3(256), 0, stream>>>(delta, x, xp, A_log, Ec, Sc);
    k_combine  <<<dim3(128),  dim3(256), 0, stream>>>(Ec, Sc, A_log, Hin);
    k_scan_full<<<dim3(512),  dim3(256), 0, stream>>>(delta, x, xp, A_log, Dp, Hin, out);
}